// Round 2
// baseline (356.250 us; speedup 1.0000x reference)
//
#include <hip/hip_runtime.h>
#include <hip/hip_bf16.h>
#include <stdint.h>

// ---- constants ----
// B=8, Cin=128, H=W=160, Ce=64, NH=4, HC=16, N=80, Cg=512, Co=128
// P: bf16, cin split in 2 chunks of 64: [ch][b][162][176][64]
//    interior (h,w) -> (h+1, w+8); borders zero.

typedef __attribute__((ext_vector_type(8))) short short8;
typedef __attribute__((ext_vector_type(4))) float f32x4;

#define GLDS(gp, lp) __builtin_amdgcn_global_load_lds(                         \
    (const __attribute__((address_space(1))) void*)(gp),                       \
    (__attribute__((address_space(3))) void*)(lp), 16, 0, 0)

__device__ __forceinline__ unsigned short f2bf(float f) {
  unsigned int u = __float_as_uint(f);
  u += 0x7fff + ((u >> 16) & 1);   // round-to-nearest-even
  return (unsigned short)(u >> 16);
}

__device__ __forceinline__ short8 zero8() {
  short8 z = {0,0,0,0,0,0,0,0};
  return z;
}

#define PCH ((size_t)8 * 162 * 176 * 64)   // elements per cin-chunk of P

// ------------------------------------------------------------------
// P0: x fp32 NCHW -> bf16 chunked-NHWC padded, zero borders
// ------------------------------------------------------------------
__global__ __launch_bounds__(192) void k_prep_x(const float* __restrict__ x,
                                                unsigned short* __restrict__ P) {
  int b = blockIdx.x / 162, hp = blockIdx.x % 162;
  int wp = threadIdx.x;
  if (wp >= 176) return;
  size_t rbase = (((size_t)b * 162 + hp) * 176 + wp) * 64;
  bool interior = (hp >= 1) && (hp <= 160) && (wp >= 8) && (wp < 168);
  if (!interior) {
    for (int cc = 0; cc < 16; ++cc)
      *(short8*)(&P[(size_t)(cc >> 3) * PCH + rbase + (cc & 7) * 8]) = zero8();
    return;
  }
  int h = hp - 1, w = wp - 8;
  const float* xb = x + (size_t)b * 128 * 25600 + h * 160 + w;
  for (int cc = 0; cc < 16; ++cc) {
    short8 v;
#pragma unroll
    for (int j = 0; j < 8; ++j) {
      float f = xb[(size_t)(cc * 8 + j) * 25600];
      v[j] = (short)f2bf(f);
    }
    *(short8*)(&P[(size_t)(cc >> 3) * PCH + rbase + (cc & 7) * 8]) = v;
  }
}

// ------------------------------------------------------------------
// P1: weight conversions + BN2 folding
//   W1t [64 ce][128 ci] bf16
//   Wpt [9 tap][2 ch][128 co][64 ci] bf16
//   s2,t2 [128] f32
// ------------------------------------------------------------------
__global__ __launch_bounds__(256) void k_prep_misc(
    const float* __restrict__ w_embed, const float* __restrict__ w_proj,
    const float* __restrict__ g2, const float* __restrict__ b2,
    const float* __restrict__ rm2, const float* __restrict__ rv2,
    unsigned short* __restrict__ W1t, unsigned short* __restrict__ Wpt,
    float* __restrict__ s2, float* __restrict__ t2) {
  int idx = blockIdx.x * 256 + threadIdx.x;
  if (idx < 8192) { W1t[idx] = f2bf(w_embed[idx]); return; }
  idx -= 8192;
  if (idx < 147456) {
    int tap = idx / 16384, r = idx - tap * 16384;   // 16384 = 2*128*64
    int ch = r >> 13, r2 = r & 8191;
    int co = r2 >> 6, ci64 = r2 & 63;
    int ci = ch * 64 + ci64;
    Wpt[idx] = f2bf(w_proj[(co * 128 + ci) * 9 + tap]);
    return;
  }
  idx -= 147456;
  if (idx < 128) {
    float s = g2[idx] * rsqrtf(rv2[idx] + 1e-3f);
    s2[idx] = s;
    t2[idx] = b2[idx] - rm2[idx] * s;
  }
}

// ------------------------------------------------------------------
// P2: guide GEMM + BN1 folding
//   Gpad [8][4][80][32] bf16  (k<16: g_raw*s1 ; k>=16: 0)
//   Cst  [8][4][80] f32       (dot(g_raw, t1) per head)
// ------------------------------------------------------------------
__global__ __launch_bounds__(64) void k_guide(
    const float* __restrict__ guide, const float* __restrict__ Wg,
    const float* __restrict__ bg, const float* __restrict__ g1,
    const float* __restrict__ b1, const float* __restrict__ rm1,
    const float* __restrict__ rv1, unsigned short* __restrict__ Gpad,
    float* __restrict__ Cst) {
  int b = blockIdx.x / 80, n = blockIdx.x % 80;
  __shared__ float gs[512];
  const float* gr = guide + ((size_t)b * 80 + n) * 512;
  for (int i = threadIdx.x; i < 512; i += 64) gs[i] = gr[i];
  __syncthreads();
  int ce = threadIdx.x;
  const float* wr = Wg + (size_t)ce * 512;
  float acc = 0.f;
  for (int k = 0; k < 512; k += 4)
    acc += gs[k] * wr[k] + gs[k + 1] * wr[k + 1] + gs[k + 2] * wr[k + 2] +
           gs[k + 3] * wr[k + 3];
  float raw = acc + bg[ce];
  float s1 = g1[ce] * rsqrtf(rv1[ce] + 1e-3f);
  float t1 = b1[ce] - rm1[ce] * s1;
  int head = ce >> 4, c = ce & 15;
  size_t gp = (((size_t)b * 4 + head) * 80 + n) * 32;
  Gpad[gp + c] = f2bf(raw * s1);
  Gpad[gp + 16 + c] = 0;
  float cp = raw * t1;
  cp += __shfl_xor(cp, 1);
  cp += __shfl_xor(cp, 2);
  cp += __shfl_xor(cp, 4);
  cp += __shfl_xor(cp, 8);
  if (c == 0) Cst[((size_t)b * 4 + head) * 80 + n] = cp;
}

// ------------------------------------------------------------------
// K2: fused embed 1x1 conv (MFMA) + per-head scores (MFMA, K padded
//     16->32; Gpad supplies zeros so E garbage at k>=16 is harmless)
//     + max over 80 guides + sigmoid -> aw [8][4][160][160]
// Block: 256 px flat (100 blocks/image), 256 thr (4 waves x 64 px)
// LDS: E [256 px][8 slots][8] bf16 = 32 KB, slot ^= px&7
// ------------------------------------------------------------------
__global__ __launch_bounds__(256, 4) void k_attn(
    const unsigned short* __restrict__ P, const unsigned short* __restrict__ W1t,
    const unsigned short* __restrict__ Gpad, const float* __restrict__ Cst,
    const float* __restrict__ attn_bias, float* __restrict__ aw) {
  __shared__ unsigned short E[16384];  // 32 KB
  int b = blockIdx.x / 100;
  int px0 = (blockIdx.x % 100) * 256;
  int tid = threadIdx.x, lane = tid & 63, wv = tid >> 6;
  int l15 = lane & 15, l4 = lane >> 4;

  // stage 1: E_raw[px][ce] = sum_cin X[px][cin] * W1[ce][cin]
  f32x4 acc[4][4];
#pragma unroll
  for (int mt = 0; mt < 4; ++mt)
#pragma unroll
    for (int nt = 0; nt < 4; ++nt) acc[mt][nt] = (f32x4){0.f, 0.f, 0.f, 0.f};

  const unsigned short* Ab[4];
#pragma unroll
  for (int mt = 0; mt < 4; ++mt) {
    int px = px0 + wv * 64 + mt * 16 + l15;
    int h = px / 160, w = px - h * 160;
    Ab[mt] = P + (((size_t)b * 162 + h + 1) * 176 + (w + 8)) * 64;
  }
#pragma unroll
  for (int kc = 0; kc < 4; ++kc) {
    int ch = kc >> 1, off = (kc & 1) * 32 + l4 * 8;
    short8 A[4], Bf[4];
#pragma unroll
    for (int mt = 0; mt < 4; ++mt)
      A[mt] = *(const short8*)(Ab[mt] + (size_t)ch * PCH + off);
#pragma unroll
    for (int nt = 0; nt < 4; ++nt)
      Bf[nt] = *(const short8*)(W1t + (nt * 16 + l15) * 128 + kc * 32 + l4 * 8);
#pragma unroll
    for (int mt = 0; mt < 4; ++mt)
#pragma unroll
      for (int nt = 0; nt < 4; ++nt)
        acc[mt][nt] = __builtin_amdgcn_mfma_f32_16x16x32_bf16(A[mt], Bf[nt],
                                                              acc[mt][nt], 0, 0, 0);
  }
  // write E: [px][slot(ce>>3) ^ (px&7)][ce&7]
#pragma unroll
  for (int mt = 0; mt < 4; ++mt)
#pragma unroll
    for (int nt = 0; nt < 4; ++nt)
#pragma unroll
      for (int r = 0; r < 4; ++r) {
        int pxl = wv * 64 + mt * 16 + l4 * 4 + r;
        int slot = (nt * 2 + (l15 >> 3)) ^ (pxl & 7);
        E[pxl * 64 + slot * 8 + (l15 & 7)] = f2bf(acc[mt][nt][r]);
      }
  __syncthreads();

  // stage 2: per head, S[n][px] = Gpad @ E_head^T ; max over n; sigmoid
  const f32x4 zf = (f32x4){0.f, 0.f, 0.f, 0.f};
#pragma unroll
  for (int head = 0; head < 4; ++head) {
    short8 Ga[5];
    f32x4 cst[5];
#pragma unroll
    for (int m5 = 0; m5 < 5; ++m5) {
      Ga[m5] = *(const short8*)(Gpad + (((size_t)b * 4 + head) * 80 + m5 * 16 + l15) * 32 + l4 * 8);
      cst[m5] = *(const f32x4*)(Cst + ((size_t)b * 4 + head) * 80 + m5 * 16 + l4 * 4);
    }
    float bias = attn_bias[head];
#pragma unroll
    for (int nt = 0; nt < 4; ++nt) {
      int pxl = wv * 64 + nt * 16 + l15;
      int rslot = (head * 2 + (l4 & 1)) ^ (pxl & 7);  // l4>=2 rereads slot l4-2: garbage-ok
      short8 Bf = *(const short8*)(&E[pxl * 64 + rslot * 8]);
      float mx = -3.0e38f;
#pragma unroll
      for (int m5 = 0; m5 < 5; ++m5) {
        f32x4 s = __builtin_amdgcn_mfma_f32_16x16x32_bf16(Ga[m5], Bf, zf, 0, 0, 0);
#pragma unroll
        for (int r = 0; r < 4; ++r) mx = fmaxf(mx, s[r] + cst[m5][r]);
      }
      mx = fmaxf(mx, __shfl_xor(mx, 16));
      mx = fmaxf(mx, __shfl_xor(mx, 32));
      if (lane < 16) {
        float v = 1.f / (1.f + __expf(-(mx * 0.25f + bias)));
        aw[((size_t)b * 4 + head) * 25600 + px0 + wv * 64 + nt * 16 + lane] = v;
      }
    }
  }
}

// ------------------------------------------------------------------
// K3: 3x3 conv as 9 shifted 1x1 GEMMs + BN + aw gate, cin K-chunked (2x64)
// Block tile: [4h x 32w px] x [128 co]; 4 waves = 2M x 2N (64px x 64co each)
// LDS: X chunk [6 rows][48 w][8 slots][8] bf16 = 36,864 B -> 4 blocks/CU
// Staged via global_load_lds (linear LDS dest, inverse-swizzled global src);
// read-side slot swizzle: slot = k8 ^ (w2&7)
// ------------------------------------------------------------------
__global__ __launch_bounds__(256, 4) void k_conv(
    const unsigned short* __restrict__ P, const unsigned short* __restrict__ Wpt,
    const float* __restrict__ s2, const float* __restrict__ t2,
    const float* __restrict__ aw, float* __restrict__ out) {
  __shared__ unsigned short X[18432];   // 36,864 B
  int blk = blockIdx.x;
  int b = blk / 200, r2 = blk % 200;
  int ht = r2 / 5, wt = r2 % 5;
  int h0 = ht * 4, w0 = wt * 32;
  int tid = threadIdx.x, lane = tid & 63, wv = tid >> 6;
  int l15 = lane & 15, l4 = lane >> 4;
  int mh = wv >> 1, nh = wv & 1;

  f32x4 acc[4][4];
#pragma unroll
  for (int j = 0; j < 4; ++j)
#pragma unroll
    for (int nt = 0; nt < 4; ++nt) acc[j][nt] = (f32x4){0.f, 0.f, 0.f, 0.f};

  int cobase[4];
#pragma unroll
  for (int nt = 0; nt < 4; ++nt) cobase[nt] = (nh * 64 + nt * 16 + l15) * 64 + l4 * 8;

  // per-lane global source offsets for staging (chunk-relative, elements)
  size_t goff[9];
#pragma unroll
  for (int i = 0; i < 9; ++i) {
    int s = (wv * 9 + i) * 64 + lane;           // LDS 16B-chunk index, 0..2303
    int row = s / 384, rem = s - row * 384;     // [6][48][8]
    int w2 = rem >> 3, slot = rem & 7;
    goff[i] = (((size_t)b * 162 + h0 + row) * 176 + (w0 + w2)) * 64 +
              (size_t)((slot ^ (w2 & 7)) * 8);
  }

  for (int ch = 0; ch < 2; ++ch) {
#pragma unroll
    for (int i = 0; i < 9; ++i)
      GLDS(P + (size_t)ch * PCH + goff[i], &X[(wv * 9 + i) * 512]);
    __syncthreads();

#pragma unroll
    for (int tap = 0; tap < 9; ++tap) {
      int ky = tap / 3, kx = tap - ky * 3;
      int rbase = mh * 2 + ky;
#pragma unroll
      for (int kc = 0; kc < 2; ++kc) {
        short8 A[4], Bf[4];
#pragma unroll
        for (int j = 0; j < 4; ++j) {
          int rb = rbase + (j >> 1);
          int wjv = (j & 1) * 16 + l15 + 7 + kx;
          A[j] = *(const short8*)(&X[((rb * 48 + wjv) * 8 + ((kc * 4 + l4) ^ (wjv & 7))) * 8]);
        }
#pragma unroll
        for (int nt = 0; nt < 4; ++nt)
          Bf[nt] = *(const short8*)(Wpt + (size_t)(tap * 2 + ch) * 8192 + cobase[nt] + kc * 32);
#pragma unroll
        for (int j = 0; j < 4; ++j)
#pragma unroll
          for (int nt = 0; nt < 4; ++nt)
            acc[j][nt] = __builtin_amdgcn_mfma_f32_16x16x32_bf16(A[j], Bf[nt],
                                                                 acc[j][nt], 0, 0, 0);
      }
    }
    if (ch == 0) __syncthreads();
  }

  // epilogue: BN + gate + store
  float s2v[4], t2v[4];
#pragma unroll
  for (int nt = 0; nt < 4; ++nt) {
    int co = nh * 64 + nt * 16 + l15;
    s2v[nt] = s2[co];
    t2v[nt] = t2[co];
  }
#pragma unroll
  for (int j = 0; j < 4; ++j) {
    int hl = mh * 2 + (j >> 1), wh = j & 1;
    int h = h0 + hl, wbase = w0 + wh * 16 + l4 * 4;
    f32x4 aw0 = *(const f32x4*)(aw + (size_t)(b * 4 + nh * 2) * 25600 + h * 160 + wbase);
    f32x4 aw1 = *(const f32x4*)(aw + (size_t)(b * 4 + nh * 2 + 1) * 25600 + h * 160 + wbase);
#pragma unroll
    for (int nt = 0; nt < 4; ++nt) {
      int co = nh * 64 + nt * 16 + l15;
      f32x4 g = (nt < 2) ? aw0 : aw1;
      f32x4 o;
#pragma unroll
      for (int r = 0; r < 4; ++r) o[r] = (acc[j][nt][r] * s2v[nt] + t2v[nt]) * g[r];
      *(f32x4*)(out + (size_t)(b * 128 + co) * 25600 + h * 160 + wbase) = o;
    }
  }
}

// ------------------------------------------------------------------
extern "C" void kernel_launch(void* const* d_in, const int* in_sizes, int n_in,
                              void* d_out, int out_size, void* d_ws, size_t ws_size,
                              hipStream_t stream) {
  (void)in_sizes; (void)n_in; (void)out_size; (void)ws_size;
  const float* x         = (const float*)d_in[0];
  const float* guide     = (const float*)d_in[1];
  const float* w_embed   = (const float*)d_in[2];
  const float* g1        = (const float*)d_in[3];
  const float* b1        = (const float*)d_in[4];
  const float* rm1       = (const float*)d_in[5];
  const float* rv1       = (const float*)d_in[6];
  const float* Wg        = (const float*)d_in[7];
  const float* bg        = (const float*)d_in[8];
  const float* attn_bias = (const float*)d_in[9];
  const float* w_proj    = (const float*)d_in[10];
  const float* g2        = (const float*)d_in[11];
  const float* b2        = (const float*)d_in[12];
  const float* rm2       = (const float*)d_in[13];
  const float* rv2       = (const float*)d_in[14];
  float* out = (float*)d_out;

  char* ws = (char*)d_ws;
  unsigned short* P    = (unsigned short*)(ws);               // 58,392,576 B
  unsigned short* W1t  = (unsigned short*)(ws + 58392576);    //     16,384 B
  unsigned short* Wpt  = (unsigned short*)(ws + 58408960);    //    294,912 B
  unsigned short* Gpad = (unsigned short*)(ws + 58703872);    //    163,840 B
  float* Cst           = (float*)(ws + 58867712);             //     10,240 B
  float* s2            = (float*)(ws + 58877952);             //        512 B
  float* t2            = (float*)(ws + 58878464);             //        512 B
  float* aw            = (float*)(ws + 58878976);             //  3,276,800 B
  // total ws usage: 62,155,776 B

  k_prep_x<<<8 * 162, 192, 0, stream>>>(x, P);
  k_prep_misc<<<609, 256, 0, stream>>>(w_embed, w_proj, g2, b2, rm2, rv2, W1t, Wpt, s2, t2);
  k_guide<<<640, 64, 0, stream>>>(guide, Wg, bg, g1, b1, rm1, rv1, Gpad, Cst);
  k_attn<<<800, 256, 0, stream>>>(P, W1t, Gpad, Cst, attn_bias, aw);
  k_conv<<<1600, 256, 0, stream>>>(P, Wpt, s2, t2, aw, out);
}

// Round 3
// 289.587 us; speedup vs baseline: 1.2302x; 1.2302x over previous
//
#include <hip/hip_runtime.h>
#include <hip/hip_bf16.h>
#include <stdint.h>

// ---- constants ----
// B=8, Cin=128, H=W=160, Ce=64, NH=4, HC=16, N=80, Cg=512, Co=128
// P: bf16 NHWC padded [8][162][176][128]; interior (h,w) -> (h+1, w+8)

typedef __attribute__((ext_vector_type(8))) short short8;
typedef __attribute__((ext_vector_type(4))) float f32x4;

__device__ __forceinline__ unsigned short f2bf(float f) {
  unsigned int u = __float_as_uint(f);
  u += 0x7fff + ((u >> 16) & 1);   // round-to-nearest-even
  return (unsigned short)(u >> 16);
}

__device__ __forceinline__ short8 zero8() {
  short8 z = {0,0,0,0,0,0,0,0};
  return z;
}

// ------------------------------------------------------------------
// P0: x fp32 NCHW -> bf16 NHWC padded [8][162][176][128], zero borders
// ------------------------------------------------------------------
__global__ __launch_bounds__(192) void k_prep_x(const float* __restrict__ x,
                                                unsigned short* __restrict__ P) {
  int b = blockIdx.x / 162, hp = blockIdx.x % 162;
  int wp = threadIdx.x;
  if (wp >= 176) return;
  size_t obase = (((size_t)b * 162 + hp) * 176 + wp) * 128;
  bool interior = (hp >= 1) && (hp <= 160) && (wp >= 8) && (wp < 168);
  if (!interior) {
    for (int cc = 0; cc < 16; ++cc) *(short8*)(&P[obase + cc * 8]) = zero8();
    return;
  }
  int h = hp - 1, w = wp - 8;
  const float* xb = x + (size_t)b * 128 * 25600 + h * 160 + w;
  for (int cc = 0; cc < 16; ++cc) {
    short8 v;
#pragma unroll
    for (int j = 0; j < 8; ++j) {
      float f = xb[(size_t)(cc * 8 + j) * 25600];
      v[j] = (short)f2bf(f);
    }
    *(short8*)(&P[obase + cc * 8]) = v;
  }
}

// ------------------------------------------------------------------
// P1: weight conversions + BN2 folding
//   W1t  [64 ce][128 ci] bf16
//   Wpt2 [9 tap][4 cs][128 co][32 ci] bf16
//   s2,t2 [128] f32
// ------------------------------------------------------------------
__global__ __launch_bounds__(256) void k_prep_misc(
    const float* __restrict__ w_embed, const float* __restrict__ w_proj,
    const float* __restrict__ g2, const float* __restrict__ b2,
    const float* __restrict__ rm2, const float* __restrict__ rv2,
    unsigned short* __restrict__ W1t, unsigned short* __restrict__ Wpt,
    float* __restrict__ s2, float* __restrict__ t2) {
  int idx = blockIdx.x * 256 + threadIdx.x;
  if (idx < 8192) { W1t[idx] = f2bf(w_embed[idx]); return; }
  idx -= 8192;
  if (idx < 147456) {
    int tap = idx / 16384, r = idx - tap * 16384;  // 16384 = 4*128*32
    int cs = r >> 12, r2 = r & 4095;
    int co = r2 >> 5, ci5 = r2 & 31;
    int ci = cs * 32 + ci5;
    Wpt[idx] = f2bf(w_proj[(co * 128 + ci) * 9 + tap]);
    return;
  }
  idx -= 147456;
  if (idx < 128) {
    float s = g2[idx] * rsqrtf(rv2[idx] + 1e-3f);
    s2[idx] = s;
    t2[idx] = b2[idx] - rm2[idx] * s;
  }
}

// ------------------------------------------------------------------
// P2: guide GEMM + BN1 folding
//   Gpad [8][4][80][32] bf16  (k<16: g_raw*s1 ; k>=16: 0)
//   Cst  [8][4][80] f32       (dot(g_raw, t1) per head)
// ------------------------------------------------------------------
__global__ __launch_bounds__(64) void k_guide(
    const float* __restrict__ guide, const float* __restrict__ Wg,
    const float* __restrict__ bg, const float* __restrict__ g1,
    const float* __restrict__ b1, const float* __restrict__ rm1,
    const float* __restrict__ rv1, unsigned short* __restrict__ Gpad,
    float* __restrict__ Cst) {
  int b = blockIdx.x / 80, n = blockIdx.x % 80;
  __shared__ float gs[512];
  const float* gr = guide + ((size_t)b * 80 + n) * 512;
  for (int i = threadIdx.x; i < 512; i += 64) gs[i] = gr[i];
  __syncthreads();
  int ce = threadIdx.x;
  const float* wr = Wg + (size_t)ce * 512;
  float acc = 0.f;
  for (int k = 0; k < 512; k += 4)
    acc += gs[k] * wr[k] + gs[k + 1] * wr[k + 1] + gs[k + 2] * wr[k + 2] +
           gs[k + 3] * wr[k + 3];
  float raw = acc + bg[ce];
  float s1 = g1[ce] * rsqrtf(rv1[ce] + 1e-3f);
  float t1 = b1[ce] - rm1[ce] * s1;
  int head = ce >> 4, c = ce & 15;
  size_t gp = (((size_t)b * 4 + head) * 80 + n) * 32;
  Gpad[gp + c] = f2bf(raw * s1);
  Gpad[gp + 16 + c] = 0;
  float cp = raw * t1;
  cp += __shfl_xor(cp, 1);
  cp += __shfl_xor(cp, 2);
  cp += __shfl_xor(cp, 4);
  cp += __shfl_xor(cp, 8);
  if (c == 0) Cst[((size_t)b * 4 + head) * 80 + n] = cp;
}

// ------------------------------------------------------------------
// K2: fused embed 1x1 conv (MFMA) + per-head scores (MFMA, K padded
//     16->32; Gpad supplies zeros so E garbage at k>=16 is harmless)
//     + max over 80 guides + sigmoid -> aw [8][4][160][160]
// Block: 256 px flat (100 blocks/image), 256 thr (4 waves x 64 px)
// LDS: E [256 px][8 slots][8] bf16 = 32 KB, slot ^= px&7
// ------------------------------------------------------------------
__global__ __launch_bounds__(256, 4) void k_attn(
    const unsigned short* __restrict__ P, const unsigned short* __restrict__ W1t,
    const unsigned short* __restrict__ Gpad, const float* __restrict__ Cst,
    const float* __restrict__ attn_bias, float* __restrict__ aw) {
  __shared__ unsigned short E[16384];  // 32 KB
  int b = blockIdx.x / 100;
  int px0 = (blockIdx.x % 100) * 256;
  int tid = threadIdx.x, lane = tid & 63, wv = tid >> 6;
  int l15 = lane & 15, l4 = lane >> 4;

  // stage 1: E_raw[px][ce] = sum_cin X[px][cin] * W1[ce][cin]
  f32x4 acc[4][4];
#pragma unroll
  for (int mt = 0; mt < 4; ++mt)
#pragma unroll
    for (int nt = 0; nt < 4; ++nt) acc[mt][nt] = (f32x4){0.f, 0.f, 0.f, 0.f};

  const unsigned short* Ab[4];
#pragma unroll
  for (int mt = 0; mt < 4; ++mt) {
    int px = px0 + wv * 64 + mt * 16 + l15;
    int h = px / 160, w = px - h * 160;
    Ab[mt] = P + (((size_t)b * 162 + h + 1) * 176 + (w + 8)) * 128;
  }
#pragma unroll
  for (int kc = 0; kc < 4; ++kc) {
    short8 A[4], Bf[4];
#pragma unroll
    for (int mt = 0; mt < 4; ++mt)
      A[mt] = *(const short8*)(Ab[mt] + kc * 32 + l4 * 8);
#pragma unroll
    for (int nt = 0; nt < 4; ++nt)
      Bf[nt] = *(const short8*)(W1t + (nt * 16 + l15) * 128 + kc * 32 + l4 * 8);
#pragma unroll
    for (int mt = 0; mt < 4; ++mt)
#pragma unroll
      for (int nt = 0; nt < 4; ++nt)
        acc[mt][nt] = __builtin_amdgcn_mfma_f32_16x16x32_bf16(A[mt], Bf[nt],
                                                              acc[mt][nt], 0, 0, 0);
  }
  // write E: [px][slot(ce>>3) ^ (px&7)][ce&7]
#pragma unroll
  for (int mt = 0; mt < 4; ++mt)
#pragma unroll
    for (int nt = 0; nt < 4; ++nt)
#pragma unroll
      for (int r = 0; r < 4; ++r) {
        int pxl = wv * 64 + mt * 16 + l4 * 4 + r;
        int slot = (nt * 2 + (l15 >> 3)) ^ (pxl & 7);
        E[pxl * 64 + slot * 8 + (l15 & 7)] = f2bf(acc[mt][nt][r]);
      }
  __syncthreads();

  // stage 2: per head, S[n][px] = Gpad @ E_head^T ; max over n; sigmoid
  const f32x4 zf = (f32x4){0.f, 0.f, 0.f, 0.f};
#pragma unroll
  for (int head = 0; head < 4; ++head) {
    short8 Ga[5];
    f32x4 cst[5];
#pragma unroll
    for (int m5 = 0; m5 < 5; ++m5) {
      Ga[m5] = *(const short8*)(Gpad + (((size_t)b * 4 + head) * 80 + m5 * 16 + l15) * 32 + l4 * 8);
      cst[m5] = *(const f32x4*)(Cst + ((size_t)b * 4 + head) * 80 + m5 * 16 + l4 * 4);
    }
    float bias = attn_bias[head];
#pragma unroll
    for (int nt = 0; nt < 4; ++nt) {
      int pxl = wv * 64 + nt * 16 + l15;
      int rslot = (head * 2 + (l4 & 1)) ^ (pxl & 7);  // l4>=2 rereads slot l4-2: garbage-ok
      short8 Bf = *(const short8*)(&E[pxl * 64 + rslot * 8]);
      float mx = -3.0e38f;
#pragma unroll
      for (int m5 = 0; m5 < 5; ++m5) {
        f32x4 s = __builtin_amdgcn_mfma_f32_16x16x32_bf16(Ga[m5], Bf, zf, 0, 0, 0);
#pragma unroll
        for (int r = 0; r < 4; ++r) mx = fmaxf(mx, s[r] + cst[m5][r]);
      }
      mx = fmaxf(mx, __shfl_xor(mx, 16));
      mx = fmaxf(mx, __shfl_xor(mx, 32));
      if (lane < 16) {
        float v = 1.f / (1.f + __expf(-(mx * 0.25f + bias)));
        aw[((size_t)b * 4 + head) * 25600 + px0 + wv * 64 + nt * 16 + lane] = v;
      }
    }
  }
}

// ------------------------------------------------------------------
// K3: 3x3 conv as 9 shifted 1x1 GEMMs + BN + aw gate.
// K (cin=128) pipelined in 4 chunks of 32, double-buffered LDS, one
// barrier per chunk (T3-minimum). Reg staging (global->reg early,
// ds_write late = T14). Pair-interleaved XOR swizzle: pixel-pair pp
// holds 8 16B-chunks, inner' = inner ^ (pp&7) -> 2-way free on both
// ds_write and ds_read.
// Block tile: [4h x 32w px] x [128 co]; 4 waves = 2M x 2N.
// LDS: 2 x [6 rows][40 px][32 ci] bf16 = 2 x 15,360 B.
// ------------------------------------------------------------------
__global__ __launch_bounds__(256, 4) void k_conv(
    const unsigned short* __restrict__ P, const unsigned short* __restrict__ Wpt,
    const float* __restrict__ s2, const float* __restrict__ t2,
    const float* __restrict__ aw, float* __restrict__ out) {
  __shared__ unsigned short X[2][7680];
  int blk = blockIdx.x;
  int b = blk / 200, r2b = blk % 200;
  int ht = r2b / 5, wt = r2b % 5;
  int h0 = ht * 4, w0 = wt * 32;
  int tid = threadIdx.x, lane = tid & 63, wv = tid >> 6;
  int l15 = lane & 15, l4 = lane >> 4;
  int mh = wv >> 1, nh = wv & 1;

  // staging decode: chunk s = i*256+tid in [0,960): LDS linear chunk s holds
  // global (r, pxl, slot) with pp=(s%160)>>3, inner=s&7, i2=inner^(pp&7),
  // pxl=pp*2+(i2>>2), slot=i2&3
  const unsigned short* gsrc[4];
#pragma unroll
  for (int i = 0; i < 4; ++i) {
    int s = i * 256 + tid;
    int r = s / 160, rem = s - r * 160;
    int pp = rem >> 3, inner = rem & 7;
    int i2 = inner ^ (pp & 7);
    int pxl = pp * 2 + (i2 >> 2), slot = i2 & 3;
    gsrc[i] = P + (((size_t)b * 162 + h0 + r) * 176 + (w0 + 7 + pxl)) * 128 + slot * 8;
  }
  bool tail = (tid < 192);  // i=3 covers chunks 768..1023; only 768..959 valid

  int cob[4];
#pragma unroll
  for (int nt = 0; nt < 4; ++nt) cob[nt] = (nh * 64 + nt * 16 + l15) * 32 + l4 * 8;

  f32x4 acc[4][4];
#pragma unroll
  for (int j = 0; j < 4; ++j)
#pragma unroll
    for (int nt = 0; nt < 4; ++nt) acc[j][nt] = (f32x4){0.f, 0.f, 0.f, 0.f};

  // A-read LDS chunk indices (per j, kx): row part added per tap
  // chunk(r,pxl,sl) = r*160 + (pxl>>1)*8 + ((((pxl&1)<<2)+sl) ^ ((pxl>>1)&7))
  int achunk[2][3];  // [whalf][kx], without row term, slot=l4
#pragma unroll
  for (int wh = 0; wh < 2; ++wh)
#pragma unroll
    for (int kx = 0; kx < 3; ++kx) {
      int pxl = wh * 16 + l15 + kx;
      int pp = pxl >> 1;
      achunk[wh][kx] = pp * 8 + ((((pxl & 1) << 2) + l4) ^ (pp & 7));
    }

  short8 stg[4];
  // prologue: stage chunk 0
#pragma unroll
  for (int i = 0; i < 4; ++i)
    if (i < 3 || tail) stg[i] = *(const short8*)(gsrc[i]);
#pragma unroll
  for (int i = 0; i < 4; ++i)
    if (i < 3 || tail) *(short8*)(&X[0][(i * 256 + tid) * 8]) = stg[i];
  __syncthreads();

#pragma unroll
  for (int cs = 0; cs < 4; ++cs) {
    // issue next chunk's global loads early (T14)
    if (cs < 3) {
#pragma unroll
      for (int i = 0; i < 4; ++i)
        if (i < 3 || tail) stg[i] = *(const short8*)(gsrc[i] + (cs + 1) * 32);
    }
    // compute on X[cs&1]
#pragma unroll
    for (int tap = 0; tap < 9; ++tap) {
      int ky = tap / 3, kx = tap - ky * 3;
      short8 A[4], Bf[4];
#pragma unroll
      for (int j = 0; j < 4; ++j) {
        int rr = mh * 2 + (j >> 1) + ky;
        A[j] = *(const short8*)(&X[cs & 1][(rr * 160 + achunk[j & 1][kx]) * 8]);
      }
#pragma unroll
      for (int nt = 0; nt < 4; ++nt)
        Bf[nt] = *(const short8*)(Wpt + (size_t)(tap * 4 + cs) * 4096 + cob[nt]);
#pragma unroll
      for (int j = 0; j < 4; ++j)
#pragma unroll
        for (int nt = 0; nt < 4; ++nt)
          acc[j][nt] = __builtin_amdgcn_mfma_f32_16x16x32_bf16(A[j], Bf[nt],
                                                               acc[j][nt], 0, 0, 0);
    }
    // write next chunk to the other buffer, then barrier
    if (cs < 3) {
#pragma unroll
      for (int i = 0; i < 4; ++i)
        if (i < 3 || tail) *(short8*)(&X[(cs + 1) & 1][(i * 256 + tid) * 8]) = stg[i];
      __syncthreads();
    }
  }

  // epilogue: BN + gate + store
  float s2v[4], t2v[4];
#pragma unroll
  for (int nt = 0; nt < 4; ++nt) {
    int co = nh * 64 + nt * 16 + l15;
    s2v[nt] = s2[co];
    t2v[nt] = t2[co];
  }
#pragma unroll
  for (int j = 0; j < 4; ++j) {
    int hl = mh * 2 + (j >> 1), wh = j & 1;
    int h = h0 + hl, wbase = w0 + wh * 16 + l4 * 4;
    f32x4 aw0 = *(const f32x4*)(aw + (size_t)(b * 4 + nh * 2) * 25600 + h * 160 + wbase);
    f32x4 aw1 = *(const f32x4*)(aw + (size_t)(b * 4 + nh * 2 + 1) * 25600 + h * 160 + wbase);
#pragma unroll
    for (int nt = 0; nt < 4; ++nt) {
      int co = nh * 64 + nt * 16 + l15;
      f32x4 g = (nt < 2) ? aw0 : aw1;
      f32x4 o;
#pragma unroll
      for (int r = 0; r < 4; ++r) o[r] = (acc[j][nt][r] * s2v[nt] + t2v[nt]) * g[r];
      *(f32x4*)(out + (size_t)(b * 128 + co) * 25600 + h * 160 + wbase) = o;
    }
  }
}

// ------------------------------------------------------------------
extern "C" void kernel_launch(void* const* d_in, const int* in_sizes, int n_in,
                              void* d_out, int out_size, void* d_ws, size_t ws_size,
                              hipStream_t stream) {
  (void)in_sizes; (void)n_in; (void)out_size; (void)ws_size;
  const float* x         = (const float*)d_in[0];
  const float* guide     = (const float*)d_in[1];
  const float* w_embed   = (const float*)d_in[2];
  const float* g1        = (const float*)d_in[3];
  const float* b1        = (const float*)d_in[4];
  const float* rm1       = (const float*)d_in[5];
  const float* rv1       = (const float*)d_in[6];
  const float* Wg        = (const float*)d_in[7];
  const float* bg        = (const float*)d_in[8];
  const float* attn_bias = (const float*)d_in[9];
  const float* w_proj    = (const float*)d_in[10];
  const float* g2        = (const float*)d_in[11];
  const float* b2        = (const float*)d_in[12];
  const float* rm2       = (const float*)d_in[13];
  const float* rv2       = (const float*)d_in[14];
  float* out = (float*)d_out;

  char* ws = (char*)d_ws;
  unsigned short* P    = (unsigned short*)(ws);               // 58,392,576 B
  unsigned short* W1t  = (unsigned short*)(ws + 58392576);    //     16,384 B
  unsigned short* Wpt  = (unsigned short*)(ws + 58408960);    //    294,912 B
  unsigned short* Gpad = (unsigned short*)(ws + 58703872);    //    163,840 B
  float* Cst           = (float*)(ws + 58867712);             //     10,240 B
  float* s2            = (float*)(ws + 58877952);             //        512 B
  float* t2            = (float*)(ws + 58878464);             //        512 B
  float* aw            = (float*)(ws + 58878976);             //  3,276,800 B
  // total ws usage: 62,155,776 B

  k_prep_x<<<8 * 162, 192, 0, stream>>>(x, P);
  k_prep_misc<<<609, 256, 0, stream>>>(w_embed, w_proj, g2, b2, rm2, rv2, W1t, Wpt, s2, t2);
  k_guide<<<640, 64, 0, stream>>>(guide, Wg, bg, g1, b1, rm1, rv1, Gpad, Cst);
  k_attn<<<800, 256, 0, stream>>>(P, W1t, Gpad, Cst, attn_bias, aw);
  k_conv<<<1600, 256, 0, stream>>>(P, Wpt, s2, t2, aw, out);
}

// Round 4
// 165.845 us; speedup vs baseline: 2.1481x; 1.7461x over previous
//
#include <hip/hip_runtime.h>
#include <hip/hip_bf16.h>
#include <stdint.h>

// ---- constants ----
// B=8, Cin=128, H=W=160, Ce=64, NH=4, HC=16, N=80, Cg=512, Co=128
// P2: bf16, cs-major planes [4 cs][8 b][162][176][32 ci]
//     interior (h,w) -> (h+1, w+8); borders zero.

typedef __attribute__((ext_vector_type(8))) short short8;
typedef __attribute__((ext_vector_type(4))) float f32x4;

#define PCH2 ((size_t)8 * 162 * 176 * 32)   // elements per cs-plane

__device__ __forceinline__ unsigned short f2bf(float f) {
  unsigned int u = __float_as_uint(f);
  u += 0x7fff + ((u >> 16) & 1);   // round-to-nearest-even
  return (unsigned short)(u >> 16);
}

__device__ __forceinline__ short8 zero8() {
  short8 z = {0,0,0,0,0,0,0,0};
  return z;
}

// ------------------------------------------------------------------
// P0: x fp32 NCHW -> bf16 cs-major padded planes, zero borders
// ------------------------------------------------------------------
__global__ __launch_bounds__(192) void k_prep_x(const float* __restrict__ x,
                                                unsigned short* __restrict__ P2) {
  int b = blockIdx.x / 162, hp = blockIdx.x % 162;
  int wp = threadIdx.x;
  if (wp >= 176) return;
  size_t pix = (((size_t)b * 162 + hp) * 176 + wp) * 32;
  bool interior = (hp >= 1) && (hp <= 160) && (wp >= 8) && (wp < 168);
  if (!interior) {
#pragma unroll
    for (int cs = 0; cs < 4; ++cs)
#pragma unroll
      for (int s = 0; s < 4; ++s)
        *(short8*)(&P2[(size_t)cs * PCH2 + pix + s * 8]) = zero8();
    return;
  }
  int h = hp - 1, w = wp - 8;
  const float* xb = x + (size_t)b * 128 * 25600 + h * 160 + w;
  for (int cs = 0; cs < 4; ++cs) {
#pragma unroll
    for (int s = 0; s < 4; ++s) {
      short8 v;
#pragma unroll
      for (int j = 0; j < 8; ++j) {
        float f = xb[(size_t)(cs * 32 + s * 8 + j) * 25600];
        v[j] = (short)f2bf(f);
      }
      *(short8*)(&P2[(size_t)cs * PCH2 + pix + s * 8]) = v;
    }
  }
}

// ------------------------------------------------------------------
// P1: weight conversions + BN2 folding
//   W1t [64 ce][128 ci] bf16
//   Wpt [4 cs][9 tap][128 co][32 ci] bf16   (slab t = cs*9+tap at t*4096)
//   s2,t2 [128] f32
// ------------------------------------------------------------------
__global__ __launch_bounds__(256) void k_prep_misc(
    const float* __restrict__ w_embed, const float* __restrict__ w_proj,
    const float* __restrict__ g2, const float* __restrict__ b2,
    const float* __restrict__ rm2, const float* __restrict__ rv2,
    unsigned short* __restrict__ W1t, unsigned short* __restrict__ Wpt,
    float* __restrict__ s2, float* __restrict__ t2) {
  int idx = blockIdx.x * 256 + threadIdx.x;
  if (idx < 8192) { W1t[idx] = f2bf(w_embed[idx]); return; }
  idx -= 8192;
  if (idx < 147456) {
    int cs = idx / 36864, r = idx - cs * 36864;
    int tap = r >> 12, r2 = r & 4095;
    int co = r2 >> 5, ci5 = r2 & 31;
    int ci = cs * 32 + ci5;
    Wpt[idx] = f2bf(w_proj[(co * 128 + ci) * 9 + tap]);
    return;
  }
  idx -= 147456;
  if (idx < 128) {
    float s = g2[idx] * rsqrtf(rv2[idx] + 1e-3f);
    s2[idx] = s;
    t2[idx] = b2[idx] - rm2[idx] * s;
  }
}

// ------------------------------------------------------------------
// P2k: guide GEMM + BN1 folding
//   Gpad [8][4][80][32] bf16  (k<16: g_raw*s1 ; k>=16: 0)
//   Cst  [8][4][80] f32       (dot(g_raw, t1) per head)
// ------------------------------------------------------------------
__global__ __launch_bounds__(64) void k_guide(
    const float* __restrict__ guide, const float* __restrict__ Wg,
    const float* __restrict__ bg, const float* __restrict__ g1,
    const float* __restrict__ b1, const float* __restrict__ rm1,
    const float* __restrict__ rv1, unsigned short* __restrict__ Gpad,
    float* __restrict__ Cst) {
  int b = blockIdx.x / 80, n = blockIdx.x % 80;
  __shared__ float gs[512];
  const float* gr = guide + ((size_t)b * 80 + n) * 512;
  for (int i = threadIdx.x; i < 512; i += 64) gs[i] = gr[i];
  __syncthreads();
  int ce = threadIdx.x;
  const float* wr = Wg + (size_t)ce * 512;
  float acc = 0.f;
  for (int k = 0; k < 512; k += 4)
    acc += gs[k] * wr[k] + gs[k + 1] * wr[k + 1] + gs[k + 2] * wr[k + 2] +
           gs[k + 3] * wr[k + 3];
  float raw = acc + bg[ce];
  float s1 = g1[ce] * rsqrtf(rv1[ce] + 1e-3f);
  float t1 = b1[ce] - rm1[ce] * s1;
  int head = ce >> 4, c = ce & 15;
  size_t gp = (((size_t)b * 4 + head) * 80 + n) * 32;
  Gpad[gp + c] = f2bf(raw * s1);
  Gpad[gp + 16 + c] = 0;
  float cp = raw * t1;
  cp += __shfl_xor(cp, 1);
  cp += __shfl_xor(cp, 2);
  cp += __shfl_xor(cp, 4);
  cp += __shfl_xor(cp, 8);
  if (c == 0) Cst[((size_t)b * 4 + head) * 80 + n] = cp;
}

// ------------------------------------------------------------------
// K2: fused embed 1x1 conv (MFMA) + per-head scores (MFMA, K padded
//     16->32; Gpad supplies zeros so E garbage at k>=16 is harmless)
//     + max over 80 guides + sigmoid -> aw [8][4][160][160]
// Block: 256 px flat, 256 thr (4 waves x 64 px); XCD-chunked: b = blk&7
// LDS: E [256 px][8 slots][8] bf16 = 32 KB, slot ^= px&7
// ------------------------------------------------------------------
__global__ __launch_bounds__(256, 4) void k_attn(
    const unsigned short* __restrict__ P2, const unsigned short* __restrict__ W1t,
    const unsigned short* __restrict__ Gpad, const float* __restrict__ Cst,
    const float* __restrict__ attn_bias, float* __restrict__ aw) {
  __shared__ unsigned short E[16384];  // 32 KB
  int b = blockIdx.x & 7;
  int px0 = (blockIdx.x >> 3) * 256;
  int tid = threadIdx.x, lane = tid & 63, wv = tid >> 6;
  int l15 = lane & 15, l4 = lane >> 4;

  // stage 1: E_raw[px][ce] = sum_cin X[px][cin] * W1[ce][cin]
  f32x4 acc[4][4];
#pragma unroll
  for (int mt = 0; mt < 4; ++mt)
#pragma unroll
    for (int nt = 0; nt < 4; ++nt) acc[mt][nt] = (f32x4){0.f, 0.f, 0.f, 0.f};

  size_t Ab[4];
#pragma unroll
  for (int mt = 0; mt < 4; ++mt) {
    int px = px0 + wv * 64 + mt * 16 + l15;
    int h = px / 160, w = px - h * 160;
    Ab[mt] = (((size_t)b * 162 + h + 1) * 176 + (w + 8)) * 32;
  }
#pragma unroll
  for (int kc = 0; kc < 4; ++kc) {
    short8 A[4], Bf[4];
#pragma unroll
    for (int mt = 0; mt < 4; ++mt)
      A[mt] = *(const short8*)(P2 + (size_t)kc * PCH2 + Ab[mt] + l4 * 8);
#pragma unroll
    for (int nt = 0; nt < 4; ++nt)
      Bf[nt] = *(const short8*)(W1t + (nt * 16 + l15) * 128 + kc * 32 + l4 * 8);
#pragma unroll
    for (int mt = 0; mt < 4; ++mt)
#pragma unroll
      for (int nt = 0; nt < 4; ++nt)
        acc[mt][nt] = __builtin_amdgcn_mfma_f32_16x16x32_bf16(A[mt], Bf[nt],
                                                              acc[mt][nt], 0, 0, 0);
  }
  // write E: [px][slot(ce>>3) ^ (px&7)][ce&7]
#pragma unroll
  for (int mt = 0; mt < 4; ++mt)
#pragma unroll
    for (int nt = 0; nt < 4; ++nt)
#pragma unroll
      for (int r = 0; r < 4; ++r) {
        int pxl = wv * 64 + mt * 16 + l4 * 4 + r;
        int slot = (nt * 2 + (l15 >> 3)) ^ (pxl & 7);
        E[pxl * 64 + slot * 8 + (l15 & 7)] = f2bf(acc[mt][nt][r]);
      }
  __syncthreads();

  // stage 2: per head, S[n][px] = Gpad @ E_head^T ; max over n; sigmoid
  const f32x4 zf = (f32x4){0.f, 0.f, 0.f, 0.f};
#pragma unroll
  for (int head = 0; head < 4; ++head) {
    short8 Ga[5];
    f32x4 cst[5];
#pragma unroll
    for (int m5 = 0; m5 < 5; ++m5) {
      Ga[m5] = *(const short8*)(Gpad + (((size_t)b * 4 + head) * 80 + m5 * 16 + l15) * 32 + l4 * 8);
      cst[m5] = *(const f32x4*)(Cst + ((size_t)b * 4 + head) * 80 + m5 * 16 + l4 * 4);
    }
    float bias = attn_bias[head];
#pragma unroll
    for (int nt = 0; nt < 4; ++nt) {
      int pxl = wv * 64 + nt * 16 + l15;
      int rslot = (head * 2 + (l4 & 1)) ^ (pxl & 7);  // l4>=2 rereads slot l4-2: garbage-ok
      short8 Bf = *(const short8*)(&E[pxl * 64 + rslot * 8]);
      float mx = -3.0e38f;
#pragma unroll
      for (int m5 = 0; m5 < 5; ++m5) {
        f32x4 s = __builtin_amdgcn_mfma_f32_16x16x32_bf16(Ga[m5], Bf, zf, 0, 0, 0);
#pragma unroll
        for (int r = 0; r < 4; ++r) mx = fmaxf(mx, s[r] + cst[m5][r]);
      }
      mx = fmaxf(mx, __shfl_xor(mx, 16));
      mx = fmaxf(mx, __shfl_xor(mx, 32));
      if (lane < 16) {
        float v = 1.f / (1.f + __expf(-(mx * 0.25f + bias)));
        aw[((size_t)b * 4 + head) * 25600 + px0 + wv * 64 + nt * 16 + lane] = v;
      }
    }
  }
}

// ------------------------------------------------------------------
// K3: 3x3 conv as 36 K-steps (cs outer 4, tap inner 9), m97-style
// double-buffered LDS for BOTH A (per cs) and B (per step), reg-staged
// with T14 issue-early/write-late. 16-B-slot XOR swizzle on A and B
// (write and read both 2-way = free). XCD-chunked: b = blk&7.
// Block tile: [4h x 32w px] x [128 co]; 4 waves = 2M x 2N.
// LDS: XA 2x15,360 B ([6][40][4][8]) + XB 2x8,192 B ([128][4][8]) = 47,104
// ------------------------------------------------------------------
__global__ __launch_bounds__(256, 3) void k_conv(
    const unsigned short* __restrict__ P2, const unsigned short* __restrict__ Wpt,
    const float* __restrict__ s2, const float* __restrict__ t2,
    const float* __restrict__ aw, float* __restrict__ out) {
  __shared__ unsigned short XA[2][7680];
  __shared__ unsigned short XB[2][4096];
  int b = blockIdx.x & 7, r2b = blockIdx.x >> 3;
  int ht = r2b / 5, wt = r2b % 5;
  int h0 = ht * 4, w0 = wt * 32;
  int tid = threadIdx.x, lane = tid & 63, wv = tid >> 6;
  int l15 = lane & 15, l4 = lane >> 4;
  int mh = wv >> 1, nh = wv & 1;

  // A staging decode: LDS chunk c=i*256+tid (linear) <- global (row,px,slot)
  // with stored slot s' holding global slot s = s' ^ ((px>>1)&3)
  size_t aoff[4];
  bool aval[4];
#pragma unroll
  for (int i = 0; i < 4; ++i) {
    int c = i * 256 + tid;
    aval[i] = (c < 960);
    int cc = aval[i] ? c : 0;
    int row = cc / 160, rem = cc - row * 160;
    int px = rem >> 2, sp = rem & 3;
    int s = sp ^ ((px >> 1) & 3);
    aoff[i] = (((size_t)b * 162 + h0 + row) * 176 + (w0 + 7 + px)) * 32 + s * 8;
  }
  // B staging decode (512 chunks, 2/thread)
  int boff[2];
#pragma unroll
  for (int i = 0; i < 2; ++i) {
    int c = i * 256 + tid;
    int co = c >> 2, sp = c & 3;
    boff[i] = co * 32 + (sp ^ ((co >> 1) & 3)) * 8;
  }
  // A-frag read chunk bases (row term added per tap)
  int abase[2][3];
#pragma unroll
  for (int wh = 0; wh < 2; ++wh)
#pragma unroll
    for (int kx = 0; kx < 3; ++kx) {
      int px = wh * 16 + l15 + kx;
      abase[wh][kx] = px * 4 + (l4 ^ ((px >> 1) & 3));
    }
  // B-frag read chunks
  int bchunk[4];
#pragma unroll
  for (int nt = 0; nt < 4; ++nt) {
    int co = nh * 64 + nt * 16 + l15;
    bchunk[nt] = co * 4 + (l4 ^ ((co >> 1) & 3));
  }

  f32x4 acc[4][4];
#pragma unroll
  for (int j = 0; j < 4; ++j)
#pragma unroll
    for (int nt = 0; nt < 4; ++nt) acc[j][nt] = (f32x4){0.f, 0.f, 0.f, 0.f};

  short8 areg[4], breg[2];
  // prologue: stage A(cs=0) and B(t=0)
#pragma unroll
  for (int i = 0; i < 4; ++i)
    if (aval[i]) areg[i] = *(const short8*)(P2 + aoff[i]);
#pragma unroll
  for (int i = 0; i < 2; ++i) breg[i] = *(const short8*)(Wpt + boff[i]);
#pragma unroll
  for (int i = 0; i < 4; ++i)
    if (aval[i]) *(short8*)(&XA[0][(i * 256 + tid) * 8]) = areg[i];
#pragma unroll
  for (int i = 0; i < 2; ++i) *(short8*)(&XB[0][(i * 256 + tid) * 8]) = breg[i];
  __syncthreads();

  for (int cs = 0; cs < 4; ++cs) {
#pragma unroll
    for (int tap = 0; tap < 9; ++tap) {
      int t = cs * 9 + tap;
      int ky = tap / 3, kx = tap - ky * 3;
      // issue-early (T14): next A chunk at tap 0, next B slab every step
      if (tap == 0 && cs < 3) {
#pragma unroll
        for (int i = 0; i < 4; ++i)
          if (aval[i]) areg[i] = *(const short8*)(P2 + (size_t)(cs + 1) * PCH2 + aoff[i]);
      }
      if (t < 35) {
#pragma unroll
        for (int i = 0; i < 2; ++i)
          breg[i] = *(const short8*)(Wpt + (size_t)(t + 1) * 4096 + boff[i]);
      }
      // frag reads + MFMA
      short8 A[4], Bf[4];
#pragma unroll
      for (int j = 0; j < 4; ++j) {
        int row = mh * 2 + (j >> 1) + ky;
        A[j] = *(const short8*)(&XA[cs & 1][(row * 160 + abase[j & 1][kx]) * 8]);
      }
#pragma unroll
      for (int nt = 0; nt < 4; ++nt)
        Bf[nt] = *(const short8*)(&XB[t & 1][bchunk[nt] * 8]);
#pragma unroll
      for (int j = 0; j < 4; ++j)
#pragma unroll
        for (int nt = 0; nt < 4; ++nt)
          acc[j][nt] = __builtin_amdgcn_mfma_f32_16x16x32_bf16(A[j], Bf[nt],
                                                               acc[j][nt], 0, 0, 0);
      // write-late into the opposite buffers
      if (t < 35) {
#pragma unroll
        for (int i = 0; i < 2; ++i)
          *(short8*)(&XB[(t + 1) & 1][(i * 256 + tid) * 8]) = breg[i];
      }
      if (tap == 8 && cs < 3) {
#pragma unroll
        for (int i = 0; i < 4; ++i)
          if (aval[i]) *(short8*)(&XA[(cs + 1) & 1][(i * 256 + tid) * 8]) = areg[i];
      }
      if (t < 35) __syncthreads();
    }
  }

  // epilogue: BN + gate + store
  float s2v[4], t2v[4];
#pragma unroll
  for (int nt = 0; nt < 4; ++nt) {
    int co = nh * 64 + nt * 16 + l15;
    s2v[nt] = s2[co];
    t2v[nt] = t2[co];
  }
#pragma unroll
  for (int j = 0; j < 4; ++j) {
    int hl = mh * 2 + (j >> 1), wh = j & 1;
    int h = h0 + hl, wbase = w0 + wh * 16 + l4 * 4;
    f32x4 aw0 = *(const f32x4*)(aw + (size_t)(b * 4 + nh * 2) * 25600 + h * 160 + wbase);
    f32x4 aw1 = *(const f32x4*)(aw + (size_t)(b * 4 + nh * 2 + 1) * 25600 + h * 160 + wbase);
#pragma unroll
    for (int nt = 0; nt < 4; ++nt) {
      int co = nh * 64 + nt * 16 + l15;
      f32x4 g = (nt < 2) ? aw0 : aw1;
      f32x4 o;
#pragma unroll
      for (int r = 0; r < 4; ++r) o[r] = (acc[j][nt][r] * s2v[nt] + t2v[nt]) * g[r];
      *(f32x4*)(out + (size_t)(b * 128 + co) * 25600 + h * 160 + wbase) = o;
    }
  }
}

// ------------------------------------------------------------------
extern "C" void kernel_launch(void* const* d_in, const int* in_sizes, int n_in,
                              void* d_out, int out_size, void* d_ws, size_t ws_size,
                              hipStream_t stream) {
  (void)in_sizes; (void)n_in; (void)out_size; (void)ws_size;
  const float* x         = (const float*)d_in[0];
  const float* guide     = (const float*)d_in[1];
  const float* w_embed   = (const float*)d_in[2];
  const float* g1        = (const float*)d_in[3];
  const float* b1        = (const float*)d_in[4];
  const float* rm1       = (const float*)d_in[5];
  const float* rv1       = (const float*)d_in[6];
  const float* Wg        = (const float*)d_in[7];
  const float* bg        = (const float*)d_in[8];
  const float* attn_bias = (const float*)d_in[9];
  const float* w_proj    = (const float*)d_in[10];
  const float* g2        = (const float*)d_in[11];
  const float* b2        = (const float*)d_in[12];
  const float* rm2       = (const float*)d_in[13];
  const float* rv2       = (const float*)d_in[14];
  float* out = (float*)d_out;

  char* ws = (char*)d_ws;
  unsigned short* P2   = (unsigned short*)(ws);               // 58,392,576 B
  unsigned short* W1t  = (unsigned short*)(ws + 58392576);    //     16,384 B
  unsigned short* Wpt  = (unsigned short*)(ws + 58408960);    //    294,912 B
  unsigned short* Gpad = (unsigned short*)(ws + 58703872);    //    163,840 B
  float* Cst           = (float*)(ws + 58867712);             //     10,240 B
  float* s2            = (float*)(ws + 58877952);             //        512 B
  float* t2            = (float*)(ws + 58878464);             //        512 B
  float* aw            = (float*)(ws + 58878976);             //  3,276,800 B
  // total ws usage: 62,155,776 B

  k_prep_x<<<8 * 162, 192, 0, stream>>>(x, P2);
  k_prep_misc<<<609, 256, 0, stream>>>(w_embed, w_proj, g2, b2, rm2, rv2, W1t, Wpt, s2, t2);
  k_guide<<<640, 64, 0, stream>>>(guide, Wg, bg, g1, b1, rm1, rv1, Gpad, Cst);
  k_attn<<<800, 256, 0, stream>>>(P2, W1t, Gpad, Cst, attn_bias, aw);
  k_conv<<<1600, 256, 0, stream>>>(P2, Wpt, s2, t2, aw, out);
}